// Round 3
// baseline (1459.454 us; speedup 1.0000x reference)
//
#include <hip/hip_runtime.h>

#define F      128       // feature width
#define BKN    96        // nodes per bucket (96*128*4B = 48KB LDS acc -> 3 blocks/CU)
#define ECAP2  3072      // bucket edge capacity (mean 1536, +34 sigma)
#define NBMAX  2048      // max buckets for fast tier (n_nodes <= 196608)
#define OVFCAP 32768     // spill-list capacity (cold correctness path)
#define BR     64        // rows per fp32-GEMM block tile (fallback)
#define KC     32        // k-chunk (fallback GEMM)

typedef short bf16x8 __attribute__((ext_vector_type(8)));
typedef float f32x4  __attribute__((ext_vector_type(4)));

__device__ __forceinline__ unsigned short f32_to_bf16_rne(float x) {
    unsigned u = __float_as_uint(x);
    u += 0x7fffu + ((u >> 16) & 1u);
    return (unsigned short)(u >> 16);
}
__device__ __forceinline__ float bf16_to_f32(unsigned short u) {
    return __uint_as_float((unsigned)u << 16);
}
// d / 96 for d < 2^20:  d/96 = (d>>5)/3, exact magic-mul for q < 131072
__device__ __forceinline__ int div_bkn(int d) {
    return (int)((((unsigned)d >> 5) * 43691u) >> 17);
}

// ---------------------------------------------------------------------------
// Kernel 0: convert W fp32 -> bf16 (64 KB only).
// ---------------------------------------------------------------------------
__global__ __launch_bounds__(256) void conv_w_kernel(
        const float* __restrict__ Wf, unsigned short* __restrict__ Wb, int n4) {
    int i = blockIdx.x * blockDim.x + threadIdx.x;
    if (i < n4) {
        float4 v = *(const float4*)(Wf + 4 * (long)i);
        ushort4 o;
        o.x = f32_to_bf16_rne(v.x);
        o.y = f32_to_bf16_rne(v.y);
        o.z = f32_to_bf16_rne(v.z);
        o.w = f32_to_bf16_rne(v.w);
        *(ushort4*)(Wb + 4 * (long)i) = o;
    }
}

// ---------------------------------------------------------------------------
// Kernel 1: h' = h @ W^T via MFMA bf16 (unchanged).
// Algebraic reorder: segment_sum(h[src]) @ W^T == segment_sum((h@W^T)[src]).
// C layout (measured m89/m91): col=lane&15, row=quad*4+reg.
// ---------------------------------------------------------------------------
__global__ __launch_bounds__(256) void gemm_h_kernel(
        const float* __restrict__ h,
        const unsigned short* __restrict__ Wb,
        unsigned short* __restrict__ hp,          // [n+1][128] bf16 out (row n = zeros)
        int n_rows) {
    const int wave = (blockIdx.x * 256 + threadIdx.x) >> 6;
    const int lane = threadIdx.x & 63;
    const int m0 = wave * 16;
    if (m0 >= n_rows) return;
    const int mn   = lane & 15;
    const int quad = lane >> 4;

    const int rowc = min(m0 + mn, n_rows - 1);
    const float* arow = h + (long)rowc * F + quad * 8;

    bf16x8 afr[4];
    #pragma unroll
    for (int kk = 0; kk < 4; ++kk) {
        float4 p0 = *(const float4*)(arow + kk * 32);
        float4 p1 = *(const float4*)(arow + kk * 32 + 4);
        bf16x8 f;
        f[0] = (short)f32_to_bf16_rne(p0.x);
        f[1] = (short)f32_to_bf16_rne(p0.y);
        f[2] = (short)f32_to_bf16_rne(p0.z);
        f[3] = (short)f32_to_bf16_rne(p0.w);
        f[4] = (short)f32_to_bf16_rne(p1.x);
        f[5] = (short)f32_to_bf16_rne(p1.y);
        f[6] = (short)f32_to_bf16_rne(p1.z);
        f[7] = (short)f32_to_bf16_rne(p1.w);
        afr[kk] = f;
    }

    f32x4 acc[8];
    #pragma unroll
    for (int t = 0; t < 8; ++t) acc[t] = (f32x4){0.f, 0.f, 0.f, 0.f};

    #pragma unroll
    for (int kk = 0; kk < 4; ++kk) {
        #pragma unroll
        for (int t = 0; t < 8; ++t) {
            const unsigned short* wp = Wb + (long)(t * 16 + mn) * F + kk * 32 + quad * 8;
            bf16x8 bfr = *(const bf16x8*)wp;
            acc[t] = __builtin_amdgcn_mfma_f32_16x16x32_bf16(afr[kk], bfr, acc[t], 0, 0, 0);
        }
    }

    #pragma unroll
    for (int t = 0; t < 8; ++t) {
        const int col = t * 16 + mn;
        #pragma unroll
        for (int r = 0; r < 4; ++r) {
            const int orow = m0 + quad * 4 + r;
            if (orow < n_rows)
                hp[(long)orow * F + col] = f32_to_bf16_rne(acc[t][r]);
        }
    }
}

// ---------------------------------------------------------------------------
// Kernel A: coarse partition into 96-node buckets.  Per-edge positioning is
// an LDS ds_add_rtn (cheap, per-CU); global atomic-returns only per
// (block, nonzero bucket) = ~256K total vs 1.6M per-edge (the 140us wall of
// rounds 1-2: global atomic-return throughput ~11 G/s is batching-invariant).
// ---------------------------------------------------------------------------
__global__ __launch_bounds__(256) void partition_kernel(
        const int* __restrict__ src,
        const int* __restrict__ dst,
        int* __restrict__ gcnt,                    // [NB], pre-zeroed
        int* __restrict__ ebuf,                    // [NB * ECAP2]
        int* __restrict__ ovf,                     // [1 + 2*OVFCAP], ovf[0] pre-zeroed
        int n_edges, int NB) {
    __shared__ int hist[NBMAX];
    __shared__ int basep[NBMAX];
    const int per = (n_edges + gridDim.x - 1) / gridDim.x;
    const int lo = blockIdx.x * per;
    const int hi = min(n_edges, lo + per);
    const int tid = threadIdx.x;

    for (int i = tid; i < NB; i += 256) hist[i] = 0;
    __syncthreads();

    for (int i = lo + tid; i < hi; i += 256)
        atomicAdd(&hist[div_bkn(dst[i])], 1);
    __syncthreads();

    for (int i = tid; i < NB; i += 256) {
        int c = hist[i];
        basep[i] = c ? atomicAdd(&gcnt[i], c) : 0;
        hist[i] = 0;
    }
    __syncthreads();

    for (int i = lo + tid; i < hi; i += 256) {
        int d = dst[i], s = src[i];
        int bkt = div_bkn(d);
        int r = atomicAdd(&hist[bkt], 1);          // ds_add_rtn_u32
        long slot = (long)basep[bkt] + r;
        if (slot < ECAP2) {
            ebuf[(long)bkt * ECAP2 + slot] = ((d - bkt * BKN) << 20) | s;
        } else {                                   // cold correctness path
            int q = atomicAdd(&ovf[0], 1);
            if (q < OVFCAP) { ovf[1 + 2 * q] = d; ovf[2 + 2 * q] = s; }
        }
    }
}

// ---------------------------------------------------------------------------
// Kernel B: LDS-accumulated aggregation + bias + relu.  One block per bucket,
// acc[96][128] fp32 in 48 KB LDS (3 blocks/CU, 24 waves/CU).  Edges need NO
// within-bucket ordering: each wave streams a slice of the bucket edge list
// (one coalesced id load per 64 edges + readlane), reads the 256 B hp row
// (irreducible random traffic), does 2 native ds_add_f32 per lane (2-way bank
// aliasing = free).  No CSR, no filtering, no per-node lists.  Epilogue
// writes each out row exactly once (no out memset).
// ---------------------------------------------------------------------------
__global__ __launch_bounds__(512) void bucket_acc_kernel(
        const unsigned short* __restrict__ hp,     // [n_nodes+1][128], row n_nodes = 0
        const int* __restrict__ gcnt,
        const int* __restrict__ ebuf,
        const int* __restrict__ ovf,
        const float* __restrict__ bias,
        float* __restrict__ out,
        int n_nodes) {
    __shared__ float acc[BKN * F];                 // 48 KB
    const int bkt = blockIdx.x;
    const int tid = threadIdx.x;
    const int lane = tid & 63;
    const int wv = tid >> 6;

    for (int i = tid; i < BKN * F; i += 512) acc[i] = 0.f;
    const int cnt = min(gcnt[bkt], ECAP2);
    const int novf = ovf[0];
    __syncthreads();

    const int* eb = ebuf + (long)bkt * ECAP2;
    for (int g = wv; g * 64 < cnt; g += 8) {
        const int idv = eb[g * 64 + lane];         // coalesced; tail slots masked below
        const int e0 = g * 64;
        for (int B = 0; B < 8; ++B) {
            #pragma unroll
            for (int j = 0; j < 8; ++j) {
                const int e = e0 + B * 8 + j;      // uniform
                int pk = __builtin_amdgcn_readlane(idv, B * 8 + j);
                int sid = (e < cnt) ? (pk & 0xFFFFF) : n_nodes;   // zero row if invalid
                int dl  = (e < cnt) ? (pk >> 20) : 0;
                unsigned v = *(const unsigned*)(hp + ((long)sid << 7) + (lane << 1));
                float* ap = acc + dl * F + (lane << 1);
                atomicAdd(ap,     __uint_as_float(v << 16));          // ds_add_f32
                atomicAdd(ap + 1, __uint_as_float(v & 0xffff0000u));  // ds_add_f32
            }
        }
    }
    __syncthreads();

    if (novf > 0) {                                // cold spill drain (never fires)
        int ne = min(novf, OVFCAP);
        for (int k = tid; k < ne; k += 512) {
            int d = ovf[1 + 2 * k];
            if (div_bkn(d) == bkt) {
                int s = ovf[2 + 2 * k];
                int dl = d - bkt * BKN;
                for (int f = 0; f < F; ++f)
                    atomicAdd(&acc[dl * F + f], bf16_to_f32(hp[(long)s * F + f]));
            }
        }
        __syncthreads();
    }

    // epilogue: bias + relu, coalesced float4 writes, each row exactly once
    const int nbase = bkt * BKN;
    for (int f4 = tid; f4 < BKN * (F / 4); f4 += 512) {
        const int nl = f4 >> 5;                    // 32 float4 per row
        const int c4 = f4 & 31;
        const int n = nbase + nl;
        if (n >= n_nodes) continue;
        float4 a = *(float4*)&acc[nl * F + c4 * 4];
        float4 bb = *(const float4*)(bias + c4 * 4);
        float4 r;
        r.x = fmaxf(a.x + bb.x, 0.f);
        r.y = fmaxf(a.y + bb.y, 0.f);
        r.z = fmaxf(a.z + bb.z, 0.f);
        r.w = fmaxf(a.w + bb.w, 0.f);
        *(float4*)(out + ((long)n << 7) + c4 * 4) = r;
    }
}

// ---------------------------------------------------------------------------
// Fallback tier (tiny ws or huge node ids): atomic scatter + fp32 GEMM.
// ---------------------------------------------------------------------------
__global__ void scatter_add_kernel(const float* __restrict__ h,
                                   const int* __restrict__ src,
                                   const int* __restrict__ dst,
                                   float* __restrict__ agg,
                                   long total) {
    long stride = (long)gridDim.x * blockDim.x;
    for (long i = (long)blockIdx.x * blockDim.x + threadIdx.x; i < total; i += stride) {
        int e    = (int)(i >> 5);
        int lane = (int)(i & 31);
        int s = src[e];
        int d = dst[e];
        float4 v = *(const float4*)(h + (long)s * F + (lane << 2));
        float* o = agg + (long)d * F + (lane << 2);
        unsafeAtomicAdd(o + 0, v.x);
        unsafeAtomicAdd(o + 1, v.y);
        unsafeAtomicAdd(o + 2, v.z);
        unsafeAtomicAdd(o + 3, v.w);
    }
}

__global__ __launch_bounds__(256) void gemm_bias_relu_inplace(
        float* __restrict__ out,
        const float* __restrict__ W,
        const float* __restrict__ bias,
        int n_rows) {
    __shared__ __align__(16) float a_t[KC][BR + 4];
    __shared__ __align__(16) float w_t[KC][F + 4];
    const int tid = threadIdx.x;
    const int tx = tid & 15;
    const int ty = tid >> 4;
    const int row0 = blockIdx.x * BR;
    float acc[4][8];
    #pragma unroll
    for (int i = 0; i < 4; ++i)
        #pragma unroll
        for (int j = 0; j < 8; ++j) acc[i][j] = 0.f;
    for (int kc = 0; kc < F; kc += KC) {
        #pragma unroll
        for (int p = 0; p < 2; ++p) {
            int q = tid + p * 256, r = q >> 3, kq = q & 7;
            int row = row0 + r;
            float4 v = make_float4(0.f, 0.f, 0.f, 0.f);
            if (row < n_rows) v = *(const float4*)(out + (long)row * F + kc + (kq << 2));
            a_t[kq * 4 + 0][r] = v.x; a_t[kq * 4 + 1][r] = v.y;
            a_t[kq * 4 + 2][r] = v.z; a_t[kq * 4 + 3][r] = v.w;
        }
        #pragma unroll
        for (int p = 0; p < 4; ++p) {
            int q = tid + p * 256, j = q >> 3, kq = q & 7;
            float4 v = *(const float4*)(W + (long)j * F + kc + (kq << 2));
            w_t[kq * 4 + 0][j] = v.x; w_t[kq * 4 + 1][j] = v.y;
            w_t[kq * 4 + 2][j] = v.z; w_t[kq * 4 + 3][j] = v.w;
        }
        __syncthreads();
        #pragma unroll
        for (int k = 0; k < KC; ++k) {
            float4 av = *(const float4*)&a_t[k][ty << 2];
            float4 w0 = *(const float4*)&w_t[k][tx << 2];
            float4 w1 = *(const float4*)&w_t[k][64 + (tx << 2)];
            float a4[4] = {av.x, av.y, av.z, av.w};
            float wv[8] = {w0.x, w0.y, w0.z, w0.w, w1.x, w1.y, w1.z, w1.w};
            #pragma unroll
            for (int i = 0; i < 4; ++i)
                #pragma unroll
                for (int j = 0; j < 8; ++j) acc[i][j] += a4[i] * wv[j];
        }
        __syncthreads();
    }
    float4 b0 = *(const float4*)(bias + (tx << 2));
    float4 b1 = *(const float4*)(bias + 64 + (tx << 2));
    #pragma unroll
    for (int i = 0; i < 4; ++i) {
        int row = row0 + (ty << 2) + i;
        if (row < n_rows) {
            float4 r0, r1;
            r0.x = fmaxf(acc[i][0] + b0.x, 0.f); r0.y = fmaxf(acc[i][1] + b0.y, 0.f);
            r0.z = fmaxf(acc[i][2] + b0.z, 0.f); r0.w = fmaxf(acc[i][3] + b0.w, 0.f);
            r1.x = fmaxf(acc[i][4] + b1.x, 0.f); r1.y = fmaxf(acc[i][5] + b1.y, 0.f);
            r1.z = fmaxf(acc[i][6] + b1.z, 0.f); r1.w = fmaxf(acc[i][7] + b1.w, 0.f);
            *(float4*)(out + (long)row * F + (tx << 2)) = r0;
            *(float4*)(out + (long)row * F + 64 + (tx << 2)) = r1;
        }
    }
}

extern "C" void kernel_launch(void* const* d_in, const int* in_sizes, int n_in,
                              void* d_out, int out_size, void* d_ws, size_t ws_size,
                              hipStream_t stream) {
    const float* h   = (const float*)d_in[0];
    const int*   src = (const int*)d_in[1];
    const int*   dst = (const int*)d_in[2];
    const float* W   = (const float*)d_in[3];
    const float* b   = (const float*)d_in[4];
    float* out = (float*)d_out;

    const int n_nodes = in_sizes[0] / F;
    const int n_edges = in_sizes[1];
    const int NB = (n_nodes + BKN - 1) / BKN;

    // ws layout: gcnt | ovf | ebuf | hp (bf16 h@W^T, +1 zero row) | Wb
    auto al16 = [](size_t x) { return (x + 15) & ~(size_t)15; };
    const size_t off_gcnt = 0;
    const size_t off_ovf  = al16((size_t)NB * 4);
    const size_t off_ebuf = al16(off_ovf + 4 + (size_t)OVFCAP * 8);
    const size_t off_hp   = al16(off_ebuf + (size_t)NB * ECAP2 * 4);
    const size_t off_wb   = al16(off_hp + (size_t)(n_nodes + 1) * F * 2);
    const size_t need     = off_wb + (size_t)F * F * 2;

    if (ws_size >= need && n_nodes > 0 && n_nodes < (1 << 20) && NB <= NBMAX) {
        int* gcnt = (int*)((char*)d_ws + off_gcnt);
        int* ovf  = (int*)((char*)d_ws + off_ovf);
        int* ebuf = (int*)((char*)d_ws + off_ebuf);
        unsigned short* hp = (unsigned short*)((char*)d_ws + off_hp);
        unsigned short* Wb = (unsigned short*)((char*)d_ws + off_wb);

        hipMemsetAsync(gcnt, 0, (size_t)NB * 4, stream);
        hipMemsetAsync(ovf, 0, 4, stream);
        hipMemsetAsync(hp + (size_t)n_nodes * F, 0, (size_t)F * 2, stream);  // zero row

        conv_w_kernel<<<(F * F / 4 + 255) / 256, 256, 0, stream>>>(W, Wb, F * F / 4);

        gemm_h_kernel<<<(n_nodes + 63) / 64, 256, 0, stream>>>(h, Wb, hp, n_nodes);

        partition_kernel<<<256, 256, 0, stream>>>(src, dst, gcnt, ebuf, ovf, n_edges, NB);

        bucket_acc_kernel<<<NB, 512, 0, stream>>>(hp, gcnt, ebuf, ovf, b, out, n_nodes);
    } else {
        hipMemsetAsync(out, 0, (size_t)out_size * sizeof(float), stream);
        scatter_add_kernel<<<16384, 256, 0, stream>>>(
            h, src, dst, out, (long)n_edges * 32);
        const int gblocks = (n_nodes + BR - 1) / BR;
        gemm_bias_relu_inplace<<<gblocks, 256, 0, stream>>>(out, W, b, n_nodes);
    }
}

// Round 4
// 252.981 us; speedup vs baseline: 5.7690x; 5.7690x over previous
//
#include <hip/hip_runtime.h>

#define F      128       // feature width
#define NPB2   256       // nodes per bucket (power of 2: bucket = d >> 8)
#define NPBS2  8
#define NBMAX2 512       // max buckets (n_nodes <= 131072); also implies n < 2^20 packing ok
#define ECAP   5120      // bucket edge cap (mean 4096 @ E/N=16, +16 sigma)
#define CHMAX  6144      // edges per partition block (LDS-sorted chunk)
#define OVFCAP 32768     // spill-list capacity (cold correctness path)
#define BR     64        // rows per fp32-GEMM block tile (fallback)
#define KC     32        // k-chunk (fallback GEMM)

typedef short bf16x8 __attribute__((ext_vector_type(8)));
typedef float f32x4  __attribute__((ext_vector_type(4)));

__device__ __forceinline__ unsigned short f32_to_bf16_rne(float x) {
    unsigned u = __float_as_uint(x);
    u += 0x7fffu + ((u >> 16) & 1u);
    return (unsigned short)(u >> 16);
}
__device__ __forceinline__ float bf16_to_f32(unsigned short u) {
    return __uint_as_float((unsigned)u << 16);
}

// ---------------------------------------------------------------------------
// Kernel 0: convert W fp32 -> bf16 (64 KB only).
// ---------------------------------------------------------------------------
__global__ __launch_bounds__(256) void conv_w_kernel(
        const float* __restrict__ Wf, unsigned short* __restrict__ Wb, int n4) {
    int i = blockIdx.x * blockDim.x + threadIdx.x;
    if (i < n4) {
        float4 v = *(const float4*)(Wf + 4 * (long)i);
        ushort4 o;
        o.x = f32_to_bf16_rne(v.x);
        o.y = f32_to_bf16_rne(v.y);
        o.z = f32_to_bf16_rne(v.z);
        o.w = f32_to_bf16_rne(v.w);
        *(ushort4*)(Wb + 4 * (long)i) = o;
    }
}

// ---------------------------------------------------------------------------
// Kernel 1: h' = h @ W^T via MFMA bf16 (unchanged, proven).
// Algebraic reorder: segment_sum(h[src]) @ W^T == segment_sum((h@W^T)[src]).
// C layout (measured m89/m91): col=lane&15, row=quad*4+reg.
// ---------------------------------------------------------------------------
__global__ __launch_bounds__(256) void gemm_h_kernel(
        const float* __restrict__ h,
        const unsigned short* __restrict__ Wb,
        unsigned short* __restrict__ hp,          // [n+1][128] bf16 out (row n = zeros)
        int n_rows) {
    const int wave = (blockIdx.x * 256 + threadIdx.x) >> 6;
    const int lane = threadIdx.x & 63;
    const int m0 = wave * 16;
    if (m0 >= n_rows) return;
    const int mn   = lane & 15;
    const int quad = lane >> 4;

    const int rowc = min(m0 + mn, n_rows - 1);
    const float* arow = h + (long)rowc * F + quad * 8;

    bf16x8 afr[4];
    #pragma unroll
    for (int kk = 0; kk < 4; ++kk) {
        float4 p0 = *(const float4*)(arow + kk * 32);
        float4 p1 = *(const float4*)(arow + kk * 32 + 4);
        bf16x8 f;
        f[0] = (short)f32_to_bf16_rne(p0.x);
        f[1] = (short)f32_to_bf16_rne(p0.y);
        f[2] = (short)f32_to_bf16_rne(p0.z);
        f[3] = (short)f32_to_bf16_rne(p0.w);
        f[4] = (short)f32_to_bf16_rne(p1.x);
        f[5] = (short)f32_to_bf16_rne(p1.y);
        f[6] = (short)f32_to_bf16_rne(p1.z);
        f[7] = (short)f32_to_bf16_rne(p1.w);
        afr[kk] = f;
    }

    f32x4 acc[8];
    #pragma unroll
    for (int t = 0; t < 8; ++t) acc[t] = (f32x4){0.f, 0.f, 0.f, 0.f};

    #pragma unroll
    for (int kk = 0; kk < 4; ++kk) {
        #pragma unroll
        for (int t = 0; t < 8; ++t) {
            const unsigned short* wp = Wb + (long)(t * 16 + mn) * F + kk * 32 + quad * 8;
            bf16x8 bfr = *(const bf16x8*)wp;
            acc[t] = __builtin_amdgcn_mfma_f32_16x16x32_bf16(afr[kk], bfr, acc[t], 0, 0, 0);
        }
    }

    #pragma unroll
    for (int t = 0; t < 8; ++t) {
        const int col = t * 16 + mn;
        #pragma unroll
        for (int r = 0; r < 4; ++r) {
            const int orow = m0 + quad * 4 + r;
            if (orow < n_rows)
                hp[(long)orow * F + col] = f32_to_bf16_rne(acc[t][r]);
        }
    }
}

// ---------------------------------------------------------------------------
// Kernel A: block-local COUNTING SORT of a 6144-edge chunk by 256-node
// bucket, then run-coalesced flush.  Eliminates the ~11 G ops/s random-4B
// wall (rounds 0-2: 1.6M scattered stores/atomic-returns = 140 us):
//  - per-edge positioning: int LDS atomics only (proven fast)
//  - global atomic-returns: one per (block, nonzero bucket) ~ 100K total
//  - global writes: sorted order -> consecutive threads hit consecutive
//    addresses within each bucket run (~64B runs), hardware-coalesced.
// ---------------------------------------------------------------------------
__global__ __launch_bounds__(512) void partition_kernel(
        const int* __restrict__ src,
        const int* __restrict__ dst,
        int* __restrict__ gcnt,                    // [NB], pre-zeroed
        int* __restrict__ ebuf,                    // [NB * ECAP]
        int* __restrict__ ovf,                     // [1 + 2*OVFCAP], ovf[0] pre-zeroed
        int n_edges, int NB) {
    __shared__ int hist[NBMAX2];
    __shared__ int delta2[NBMAX2];                 // gbase - local_excl_offset
    __shared__ int cursor[NBMAX2];
    __shared__ int sval[CHMAX];                    // sorted packed (dl<<20)|src
    __shared__ unsigned short sbkt[CHMAX];         // sorted bucket id
    __shared__ int wsum[8];

    const int tid = threadIdx.x;
    const int lane = tid & 63;
    const int w = tid >> 6;
    const int lo = blockIdx.x * CHMAX;
    const int hi = min(n_edges, lo + CHMAX);
    const int len = hi - lo;

    for (int i = tid; i < NB; i += 512) hist[i] = 0;
    __syncthreads();

    // pass 1: bucket histogram (int LDS atomics)
    for (int i = lo + tid; i < hi; i += 512)
        atomicAdd(&hist[((unsigned)dst[i]) >> NPBS2], 1);
    __syncthreads();

    // block-wide exclusive scan over NB (<=512) counters
    int v = (tid < NB) ? hist[tid] : 0;
    const int own = v;
    #pragma unroll
    for (int d = 1; d < 64; d <<= 1) { int u = __shfl_up(v, d); if (lane >= d) v += u; }
    if (lane == 63) wsum[w] = v;
    __syncthreads();
    if (w == 0) {
        int s = (lane < 8) ? wsum[lane] : 0;
        #pragma unroll
        for (int d = 1; d < 8; d <<= 1) { int u = __shfl_up(s, d); if (lane >= d) s += u; }
        if (lane < 8) wsum[lane] = s;
    }
    __syncthreads();
    const int excl = v - own + ((w > 0) ? wsum[w - 1] : 0);
    if (tid < NB) {
        int gbase = own ? atomicAdd(&gcnt[tid], own) : 0;   // one return per bucket
        delta2[tid] = gbase - excl;
        cursor[tid] = excl;
    }
    __syncthreads();

    // pass 2: scatter into LDS sorted-by-bucket arrays (int LDS atomic rtn)
    for (int i = lo + tid; i < hi; i += 512) {
        int d = dst[i], s = src[i];
        int b = ((unsigned)d) >> NPBS2;
        int p = atomicAdd(&cursor[b], 1);          // ds_add_rtn_u32, p < len
        sval[p] = ((d & (NPB2 - 1)) << 20) | s;
        sbkt[p] = (unsigned short)b;
    }
    __syncthreads();

    // flush: consecutive i -> consecutive global slots within each run
    for (int i = tid; i < len; i += 512) {
        int vv = sval[i];
        int b = sbkt[i];
        int slot = i + delta2[b];
        if (slot < ECAP) {
            ebuf[(long)b * ECAP + slot] = vv;
        } else {                                   // cold correctness path
            int q = atomicAdd(&ovf[0], 1);
            if (q < OVFCAP) {
                ovf[1 + 2 * q] = (b << NPBS2) | (vv >> 20);
                ovf[2 + 2 * q] = vv & 0xFFFFF;
            }
        }
    }
}

// ---------------------------------------------------------------------------
// Kernel B: per-bucket CSR (second counting sort, int LDS atomics only) +
// round-0's proven register-accumulation inner loop + fused bias+relu.
// One block per 256-node bucket, 8 waves x 32 nodes.  No filter passes, no
// redundant rescans, no fp32 atomics anywhere.  Each out row written once.
// ---------------------------------------------------------------------------
__global__ __launch_bounds__(512) void bucket_gather_kernel(
        const unsigned short* __restrict__ hp,     // [n_nodes+1][128], row n_nodes = 0
        const int* __restrict__ gcnt,
        const int* __restrict__ ebuf,
        const int* __restrict__ ovf,
        const float* __restrict__ bias,
        float* __restrict__ out,
        int n_nodes) {
    __shared__ int hist[NPB2];
    __shared__ int ofs[NPB2];
    __shared__ int cur[NPB2];
    __shared__ int srt[ECAP];                      // per-node src-id segments
    __shared__ int wsum[8];

    const int bkt = blockIdx.x;
    const int tid = threadIdx.x;
    const int lane = tid & 63;
    const int w = tid >> 6;
    const int cnt = min(gcnt[bkt], ECAP);
    const int novf = ovf[0];

    if (tid < NPB2) hist[tid] = 0;
    __syncthreads();

    const int* eb = ebuf + (long)bkt * ECAP;
    // pass 1: per-node degree histogram
    for (int i = tid; i < cnt; i += 512)
        atomicAdd(&hist[((unsigned)eb[i]) >> 20], 1);
    __syncthreads();

    // exclusive scan over 256 degrees
    int v = (tid < NPB2) ? hist[tid] : 0;
    const int own = v;
    #pragma unroll
    for (int d = 1; d < 64; d <<= 1) { int u = __shfl_up(v, d); if (lane >= d) v += u; }
    if (lane == 63) wsum[w] = v;
    __syncthreads();
    if (w == 0) {
        int s = (lane < 8) ? wsum[lane] : 0;
        #pragma unroll
        for (int d = 1; d < 8; d <<= 1) { int u = __shfl_up(s, d); if (lane >= d) s += u; }
        if (lane < 8) wsum[lane] = s;
    }
    __syncthreads();
    if (tid < NPB2) {
        int e = v - own + ((w > 0) ? wsum[w - 1] : 0);
        ofs[tid] = e;
        cur[tid] = e;
    }
    __syncthreads();

    // pass 2: scatter src ids into per-node segments
    for (int i = tid; i < cnt; i += 512) {
        int vv = eb[i];
        int p = atomicAdd(&cur[vv >> 20], 1);      // ds_add_rtn_u32
        srt[p] = vv & 0xFFFFF;
    }
    __syncthreads();

    // per-node register accumulation (round-0 inner loop), 2 feats per lane
    const float2 bv = *(const float2*)(bias + (lane << 1));
    for (int nl = w; nl < NPB2; nl += 8) {
        const int n = (bkt << NPBS2) + nl;
        if (n >= n_nodes) break;
        const int beg = ofs[nl];
        const int end = beg + hist[nl];

        float ax = 0.f, ay = 0.f;
        for (int i = beg; i < end; i += 8) {       // 8 row loads in flight
            unsigned vv[8]; bool val[8];
            #pragma unroll
            for (int j = 0; j < 8; ++j) {
                val[j] = (i + j) < end;
                int sid = srt[val[j] ? i + j : beg];   // uniform -> ds broadcast
                vv[j] = *(const unsigned*)(hp + ((long)sid << 7) + (lane << 1));
            }
            #pragma unroll
            for (int j = 0; j < 8; ++j) {
                if (val[j]) {
                    ax += __uint_as_float(vv[j] << 16);
                    ay += __uint_as_float(vv[j] & 0xffff0000u);
                }
            }
        }

        if (novf > 0) {                            // cold spill drain (never fires)
            int ne = min(novf, OVFCAP);
            for (int k = 0; k < ne; ++k) {
                if (ovf[1 + 2 * k] == n) {
                    int s = ovf[2 + 2 * k];
                    unsigned u = *(const unsigned*)(hp + ((long)s << 7) + (lane << 1));
                    ax += __uint_as_float(u << 16);
                    ay += __uint_as_float(u & 0xffff0000u);
                }
            }
        }

        float* o = out + ((long)n << 7) + (lane << 1);
        float rx = fmaxf(ax + bv.x, 0.f);
        float ry = fmaxf(ay + bv.y, 0.f);
        *(float2*)o = make_float2(rx, ry);
    }
}

// ---------------------------------------------------------------------------
// Fallback tier (tiny ws or huge node ids): atomic scatter + fp32 GEMM.
// ---------------------------------------------------------------------------
__global__ void scatter_add_kernel(const float* __restrict__ h,
                                   const int* __restrict__ src,
                                   const int* __restrict__ dst,
                                   float* __restrict__ agg,
                                   long total) {
    long stride = (long)gridDim.x * blockDim.x;
    for (long i = (long)blockIdx.x * blockDim.x + threadIdx.x; i < total; i += stride) {
        int e    = (int)(i >> 5);
        int lane = (int)(i & 31);
        int s = src[e];
        int d = dst[e];
        float4 v = *(const float4*)(h + (long)s * F + (lane << 2));
        float* o = agg + (long)d * F + (lane << 2);
        unsafeAtomicAdd(o + 0, v.x);
        unsafeAtomicAdd(o + 1, v.y);
        unsafeAtomicAdd(o + 2, v.z);
        unsafeAtomicAdd(o + 3, v.w);
    }
}

__global__ __launch_bounds__(256) void gemm_bias_relu_inplace(
        float* __restrict__ out,
        const float* __restrict__ W,
        const float* __restrict__ bias,
        int n_rows) {
    __shared__ __align__(16) float a_t[KC][BR + 4];
    __shared__ __align__(16) float w_t[KC][F + 4];
    const int tid = threadIdx.x;
    const int tx = tid & 15;
    const int ty = tid >> 4;
    const int row0 = blockIdx.x * BR;
    float acc[4][8];
    #pragma unroll
    for (int i = 0; i < 4; ++i)
        #pragma unroll
        for (int j = 0; j < 8; ++j) acc[i][j] = 0.f;
    for (int kc = 0; kc < F; kc += KC) {
        #pragma unroll
        for (int p = 0; p < 2; ++p) {
            int q = tid + p * 256, r = q >> 3, kq = q & 7;
            int row = row0 + r;
            float4 v = make_float4(0.f, 0.f, 0.f, 0.f);
            if (row < n_rows) v = *(const float4*)(out + (long)row * F + kc + (kq << 2));
            a_t[kq * 4 + 0][r] = v.x; a_t[kq * 4 + 1][r] = v.y;
            a_t[kq * 4 + 2][r] = v.z; a_t[kq * 4 + 3][r] = v.w;
        }
        #pragma unroll
        for (int p = 0; p < 4; ++p) {
            int q = tid + p * 256, j = q >> 3, kq = q & 7;
            float4 v = *(const float4*)(W + (long)j * F + kc + (kq << 2));
            w_t[kq * 4 + 0][j] = v.x; w_t[kq * 4 + 1][j] = v.y;
            w_t[kq * 4 + 2][j] = v.z; w_t[kq * 4 + 3][j] = v.w;
        }
        __syncthreads();
        #pragma unroll
        for (int k = 0; k < KC; ++k) {
            float4 av = *(const float4*)&a_t[k][ty << 2];
            float4 w0 = *(const float4*)&w_t[k][tx << 2];
            float4 w1 = *(const float4*)&w_t[k][64 + (tx << 2)];
            float a4[4] = {av.x, av.y, av.z, av.w};
            float wv[8] = {w0.x, w0.y, w0.z, w0.w, w1.x, w1.y, w1.z, w1.w};
            #pragma unroll
            for (int i = 0; i < 4; ++i)
                #pragma unroll
                for (int j = 0; j < 8; ++j) acc[i][j] += a4[i] * wv[j];
        }
        __syncthreads();
    }
    float4 b0 = *(const float4*)(bias + (tx << 2));
    float4 b1 = *(const float4*)(bias + 64 + (tx << 2));
    #pragma unroll
    for (int i = 0; i < 4; ++i) {
        int row = row0 + (ty << 2) + i;
        if (row < n_rows) {
            float4 r0, r1;
            r0.x = fmaxf(acc[i][0] + b0.x, 0.f); r0.y = fmaxf(acc[i][1] + b0.y, 0.f);
            r0.z = fmaxf(acc[i][2] + b0.z, 0.f); r0.w = fmaxf(acc[i][3] + b0.w, 0.f);
            r1.x = fmaxf(acc[i][4] + b1.x, 0.f); r1.y = fmaxf(acc[i][5] + b1.y, 0.f);
            r1.z = fmaxf(acc[i][6] + b1.z, 0.f); r1.w = fmaxf(acc[i][7] + b1.w, 0.f);
            *(float4*)(out + (long)row * F + (tx << 2)) = r0;
            *(float4*)(out + (long)row * F + 64 + (tx << 2)) = r1;
        }
    }
}

extern "C" void kernel_launch(void* const* d_in, const int* in_sizes, int n_in,
                              void* d_out, int out_size, void* d_ws, size_t ws_size,
                              hipStream_t stream) {
    const float* h   = (const float*)d_in[0];
    const int*   src = (const int*)d_in[1];
    const int*   dst = (const int*)d_in[2];
    const float* W   = (const float*)d_in[3];
    const float* b   = (const float*)d_in[4];
    float* out = (float*)d_out;

    const int n_nodes = in_sizes[0] / F;
    const int n_edges = in_sizes[1];
    const int NB = (n_nodes + NPB2 - 1) >> NPBS2;

    // ws layout: gcnt | ovf | ebuf | hp (bf16 h@W^T, +1 zero row) | Wb
    auto al16 = [](size_t x) { return (x + 15) & ~(size_t)15; };
    const size_t off_gcnt = 0;
    const size_t off_ovf  = al16((size_t)NB * 4);
    const size_t off_ebuf = al16(off_ovf + 4 + (size_t)OVFCAP * 8);
    const size_t off_hp   = al16(off_ebuf + (size_t)NB * ECAP * 4);
    const size_t off_wb   = al16(off_hp + (size_t)(n_nodes + 1) * F * 2);
    const size_t need     = off_wb + (size_t)F * F * 2;

    if (ws_size >= need && n_nodes > 0 && NB <= NBMAX2) {
        int* gcnt = (int*)((char*)d_ws + off_gcnt);
        int* ovf  = (int*)((char*)d_ws + off_ovf);
        int* ebuf = (int*)((char*)d_ws + off_ebuf);
        unsigned short* hp = (unsigned short*)((char*)d_ws + off_hp);
        unsigned short* Wb = (unsigned short*)((char*)d_ws + off_wb);

        hipMemsetAsync(gcnt, 0, (size_t)NB * 4, stream);
        hipMemsetAsync(ovf, 0, 4, stream);
        hipMemsetAsync(hp + (size_t)n_nodes * F, 0, (size_t)F * 2, stream);  // zero row

        conv_w_kernel<<<(F * F / 4 + 255) / 256, 256, 0, stream>>>(W, Wb, F * F / 4);

        gemm_h_kernel<<<(n_nodes + 63) / 64, 256, 0, stream>>>(h, Wb, hp, n_nodes);

        const int pgrid = (n_edges + CHMAX - 1) / CHMAX;
        partition_kernel<<<pgrid, 512, 0, stream>>>(src, dst, gcnt, ebuf, ovf,
                                                    n_edges, NB);

        bucket_gather_kernel<<<NB, 512, 0, stream>>>(hp, gcnt, ebuf, ovf, b,
                                                     out, n_nodes);
    } else {
        hipMemsetAsync(out, 0, (size_t)out_size * sizeof(float), stream);
        scatter_add_kernel<<<16384, 256, 0, stream>>>(
            h, src, dst, out, (long)n_edges * 32);
        const int gblocks = (n_nodes + BR - 1) / BR;
        gemm_bias_relu_inplace<<<gblocks, 256, 0, stream>>>(out, W, b, n_nodes);
    }
}

// Round 5
// 220.866 us; speedup vs baseline: 6.6079x; 1.1454x over previous
//
#include <hip/hip_runtime.h>

#define F      128       // feature width
#define NPB    256       // nodes per bucket
#define NPBS   8
#define NBMAX  512       // max buckets (scan width); implies n_nodes <= 131072 < 2^20
#define ECAP   5120      // bucket edge cap (mean 4096 @ E/N=16, +16 sigma)
#define CHMAX  4096      // edges per sort chunk
#define CH_PT  4         // CHMAX / 1024
#define OVFCAP 32768     // spill-list capacity (cold correctness path)
#define BR     64        // rows per fp32-GEMM block tile (fallback)
#define KC     32        // k-chunk (fallback GEMM)

typedef short bf16x8 __attribute__((ext_vector_type(8)));
typedef float f32x4  __attribute__((ext_vector_type(4)));

__device__ __forceinline__ unsigned short f32_to_bf16_rne(float x) {
    unsigned u = __float_as_uint(x);
    u += 0x7fffu + ((u >> 16) & 1u);
    return (unsigned short)(u >> 16);
}
__device__ __forceinline__ float bf16_to_f32(unsigned short u) {
    return __uint_as_float((unsigned)u << 16);
}

// ---------------------------------------------------------------------------
// Kernel 0: convert W fp32 -> bf16 (64 KB only).
// ---------------------------------------------------------------------------
__global__ __launch_bounds__(256) void conv_w_kernel(
        const float* __restrict__ Wf, unsigned short* __restrict__ Wb, int n4) {
    int i = blockIdx.x * blockDim.x + threadIdx.x;
    if (i < n4) {
        float4 v = *(const float4*)(Wf + 4 * (long)i);
        ushort4 o;
        o.x = f32_to_bf16_rne(v.x);
        o.y = f32_to_bf16_rne(v.y);
        o.z = f32_to_bf16_rne(v.z);
        o.w = f32_to_bf16_rne(v.w);
        *(ushort4*)(Wb + 4 * (long)i) = o;
    }
}

// ---------------------------------------------------------------------------
// Kernel 1: h' = h @ W^T via MFMA bf16 (unchanged, proven).
// Algebraic reorder: segment_sum(h[src]) @ W^T == segment_sum((h@W^T)[src]).
// C layout (measured m89/m91): col=lane&15, row=quad*4+reg.
// ---------------------------------------------------------------------------
__global__ __launch_bounds__(256) void gemm_h_kernel(
        const float* __restrict__ h,
        const unsigned short* __restrict__ Wb,
        unsigned short* __restrict__ hp,          // [n][128] bf16 out
        int n_rows) {
    const int wave = (blockIdx.x * 256 + threadIdx.x) >> 6;
    const int lane = threadIdx.x & 63;
    const int m0 = wave * 16;
    if (m0 >= n_rows) return;
    const int mn   = lane & 15;
    const int quad = lane >> 4;

    const int rowc = min(m0 + mn, n_rows - 1);
    const float* arow = h + (long)rowc * F + quad * 8;

    bf16x8 afr[4];
    #pragma unroll
    for (int kk = 0; kk < 4; ++kk) {
        float4 p0 = *(const float4*)(arow + kk * 32);
        float4 p1 = *(const float4*)(arow + kk * 32 + 4);
        bf16x8 f;
        f[0] = (short)f32_to_bf16_rne(p0.x);
        f[1] = (short)f32_to_bf16_rne(p0.y);
        f[2] = (short)f32_to_bf16_rne(p0.z);
        f[3] = (short)f32_to_bf16_rne(p0.w);
        f[4] = (short)f32_to_bf16_rne(p1.x);
        f[5] = (short)f32_to_bf16_rne(p1.y);
        f[6] = (short)f32_to_bf16_rne(p1.z);
        f[7] = (short)f32_to_bf16_rne(p1.w);
        afr[kk] = f;
    }

    f32x4 acc[8];
    #pragma unroll
    for (int t = 0; t < 8; ++t) acc[t] = (f32x4){0.f, 0.f, 0.f, 0.f};

    #pragma unroll
    for (int kk = 0; kk < 4; ++kk) {
        #pragma unroll
        for (int t = 0; t < 8; ++t) {
            const unsigned short* wp = Wb + (long)(t * 16 + mn) * F + kk * 32 + quad * 8;
            bf16x8 bfr = *(const bf16x8*)wp;
            acc[t] = __builtin_amdgcn_mfma_f32_16x16x32_bf16(afr[kk], bfr, acc[t], 0, 0, 0);
        }
    }

    #pragma unroll
    for (int t = 0; t < 8; ++t) {
        const int col = t * 16 + mn;
        #pragma unroll
        for (int r = 0; r < 4; ++r) {
            const int orow = m0 + quad * 4 + r;
            if (orow < n_rows)
                hp[(long)orow * F + col] = f32_to_bf16_rne(acc[t][r]);
        }
    }
}

// ---------------------------------------------------------------------------
// Kernel A1: per-chunk bucket histogram -> cntmat[chunk][bucket] (coalesced).
// No global atomics (round 1/2 lesson: random atomic-returns wall at ~0.7TB/s
// RMW; round 4 lesson: 8-wave blocks at 1 block/CU = 25% occupancy).
// ---------------------------------------------------------------------------
__global__ __launch_bounds__(1024) void count_kernel(
        const int* __restrict__ dst,
        int* __restrict__ cntmat,                  // [NBLK][NB]
        int n_edges, int NB) {
    __shared__ int hist[NBMAX];
    const int tid = threadIdx.x;
    const int lo = blockIdx.x * CHMAX;
    const int hi = min(n_edges, lo + CHMAX);
    for (int i = tid; i < NB; i += 1024) hist[i] = 0;
    __syncthreads();
    for (int i = lo + tid; i < hi; i += 1024)
        atomicAdd(&hist[((unsigned)dst[i]) >> NPBS], 1);
    __syncthreads();
    int* row = cntmat + (long)blockIdx.x * NB;
    for (int i = tid; i < NB; i += 1024) row[i] = hist[i];
}

// ---------------------------------------------------------------------------
// Kernel A2: per-bucket exclusive prefix over chunks (in place) + gcnt total.
// One block per bucket; column reads are L2-resident (cntmat ~0.6 MB).
// Deterministic bases -> the scatter needs no atomic-returns at all.
// ---------------------------------------------------------------------------
__global__ __launch_bounds__(256) void scan_kernel(
        int* __restrict__ cntmat, int* __restrict__ gcnt, int NB, int NBLK) {
    __shared__ int wsum[4];
    const int b = blockIdx.x;
    const int tid = threadIdx.x;
    const int lane = tid & 63;
    const int w = tid >> 6;
    int carry = 0;
    for (int c0 = 0; c0 < NBLK; c0 += 256) {
        const int blk = c0 + tid;
        const int own = (blk < NBLK) ? cntmat[(long)blk * NB + b] : 0;
        int v = own;
        #pragma unroll
        for (int d = 1; d < 64; d <<= 1) { int u = __shfl_up(v, d); if (lane >= d) v += u; }
        if (lane == 63) wsum[w] = v;
        __syncthreads();
        if (w == 0) {
            int s = (lane < 4) ? wsum[lane] : 0;
            #pragma unroll
            for (int d = 1; d < 4; d <<= 1) { int u = __shfl_up(s, d); if (lane >= d) s += u; }
            if (lane < 4) wsum[lane] = s;
        }
        __syncthreads();
        const int excl = v - own + ((w > 0) ? wsum[w - 1] : 0) + carry;
        if (blk < NBLK) cntmat[(long)blk * NB + b] = excl;
        carry += wsum[3];
        __syncthreads();
    }
    if (tid == 0) gcnt[b] = carry;
}

// ---------------------------------------------------------------------------
// Kernel A3: register-staged counting sort of a 4096-edge chunk + coalesced
// run flush into bucket-segmented ebuf.  Edges read from global ONCE into
// registers, all positioning via int LDS atomics, global base from cntmat
// (plain coalesced load).  Runs ~10 edges (~42B) keep writes far above the
// random-line RMW wall.
// ---------------------------------------------------------------------------
__global__ __launch_bounds__(1024) void scatter_kernel(
        const int* __restrict__ src,
        const int* __restrict__ dst,
        const int* __restrict__ cntmat,
        int* __restrict__ ebuf,                    // [NB * ECAP]
        int* __restrict__ ovf,                     // [1 + 2*OVFCAP], ovf[0] pre-zeroed
        int n_edges, int NB) {
    __shared__ int hist[NBMAX];
    __shared__ int dlt[NBMAX];
    __shared__ int cursor[NBMAX];
    __shared__ int sval[CHMAX];
    __shared__ unsigned short sbkt[CHMAX];
    __shared__ int wsum[16];
    const int tid = threadIdx.x;
    const int lane = tid & 63;
    const int w = tid >> 6;
    const int lo = blockIdx.x * CHMAX;
    const int hi = min(n_edges, lo + CHMAX);
    const int len = hi - lo;

    int dd[CH_PT], ss[CH_PT];
    #pragma unroll
    for (int k = 0; k < CH_PT; ++k) {
        int i = lo + k * 1024 + tid;
        bool ok = i < hi;
        dd[k] = ok ? dst[i] : -1;
        ss[k] = ok ? src[i] : 0;
    }
    for (int i = tid; i < NB; i += 1024) hist[i] = 0;
    __syncthreads();

    #pragma unroll
    for (int k = 0; k < CH_PT; ++k)
        if (dd[k] >= 0) atomicAdd(&hist[((unsigned)dd[k]) >> NPBS], 1);
    __syncthreads();

    const int own = (tid < NB) ? hist[tid] : 0;
    int v = own;
    #pragma unroll
    for (int d = 1; d < 64; d <<= 1) { int u = __shfl_up(v, d); if (lane >= d) v += u; }
    if (lane == 63) wsum[w] = v;
    __syncthreads();
    if (w == 0) {
        int s = (lane < 16) ? wsum[lane] : 0;
        #pragma unroll
        for (int d = 1; d < 16; d <<= 1) { int u = __shfl_up(s, d); if (lane >= d) s += u; }
        if (lane < 16) wsum[lane] = s;
    }
    __syncthreads();
    if (tid < NB) {
        const int excl = v - own + ((w > 0) ? wsum[w - 1] : 0);
        dlt[tid] = cntmat[(long)blockIdx.x * NB + tid] - excl;   // global base - local base
        cursor[tid] = excl;
    }
    __syncthreads();

    #pragma unroll
    for (int k = 0; k < CH_PT; ++k)
        if (dd[k] >= 0) {
            int b = ((unsigned)dd[k]) >> NPBS;
            int p = atomicAdd(&cursor[b], 1);      // ds_add_rtn_u32, p < len
            sval[p] = ((dd[k] & (NPB - 1)) << 20) | ss[k];
            sbkt[p] = (unsigned short)b;
        }
    __syncthreads();

    for (int i = tid; i < len; i += 1024) {
        int vv = sval[i];
        int b = sbkt[i];
        int slot = i + dlt[b];
        if (slot < ECAP) {
            ebuf[(long)b * ECAP + slot] = vv;
        } else {                                   // cold correctness path
            int q = atomicAdd(&ovf[0], 1);
            if (q < OVFCAP) {
                ovf[1 + 2 * q] = (b << NPBS) | (vv >> 20);
                ovf[2 + 2 * q] = vv & 0xFFFFF;
            }
        }
    }
}

// ---------------------------------------------------------------------------
// Kernel B: per-bucket CSR build + register accumulation + fused bias+relu.
// 1024 threads = 16 waves x 16 nodes (round-4 fix: 8-wave blocks at 1.5
// blocks/CU gave 27.7% occupancy; 16-wave blocks give ~24 waves/CU).  Edge
// list register-staged (one global pass); hot-loop addressing via 32-bit
// voffset + SGPR base (saves ~2-3 VALU/edge vs 64-bit pointer arithmetic).
// ---------------------------------------------------------------------------
__global__ __launch_bounds__(1024) void bucket_gather_kernel(
        const unsigned short* __restrict__ hp,     // [n_nodes][128]
        const int* __restrict__ gcnt,
        const int* __restrict__ ebuf,
        const int* __restrict__ ovf,
        const float* __restrict__ bias,
        float* __restrict__ out,
        int n_nodes) {
    __shared__ int hist[NPB];
    __shared__ int ofs[NPB];
    __shared__ int cur[NPB];
    __shared__ int srt[ECAP];
    __shared__ int wsum[16];
    const int bkt = blockIdx.x;
    const int tid = threadIdx.x;
    const int lane = tid & 63;
    const int w = tid >> 6;
    const int cnt = min(gcnt[bkt], ECAP);
    const int novf = ovf[0];
    const int* eb = ebuf + (long)bkt * ECAP;

    int ev[5];                                     // 5*1024 = 5120 = ECAP coverage
    #pragma unroll
    for (int k = 0; k < 5; ++k) {
        int i = k * 1024 + tid;
        ev[k] = (i < cnt) ? eb[i] : -1;
    }
    if (tid < NPB) hist[tid] = 0;
    __syncthreads();

    #pragma unroll
    for (int k = 0; k < 5; ++k)
        if (ev[k] >= 0) atomicAdd(&hist[((unsigned)ev[k]) >> 20], 1);
    __syncthreads();

    const int own = (tid < NPB) ? hist[tid] : 0;
    int v = own;
    #pragma unroll
    for (int d = 1; d < 64; d <<= 1) { int u = __shfl_up(v, d); if (lane >= d) v += u; }
    if (lane == 63) wsum[w] = v;
    __syncthreads();
    if (w == 0) {
        int s = (lane < 16) ? wsum[lane] : 0;
        #pragma unroll
        for (int d = 1; d < 16; d <<= 1) { int u = __shfl_up(s, d); if (lane >= d) s += u; }
        if (lane < 16) wsum[lane] = s;
    }
    __syncthreads();
    if (tid < NPB) {
        const int e = v - own + ((w > 0) ? wsum[w - 1] : 0);
        ofs[tid] = e;
        cur[tid] = e;
    }
    __syncthreads();

    #pragma unroll
    for (int k = 0; k < 5; ++k)
        if (ev[k] >= 0) {
            int p = atomicAdd(&cur[((unsigned)ev[k]) >> 20], 1);
            srt[p] = ev[k] & 0xFFFFF;
        }
    __syncthreads();

    const unsigned lo4 = lane << 2;                // byte offset of this lane's dword
    const float2 bv = *(const float2*)(bias + (lane << 1));
    for (int nl = w; nl < NPB; nl += 16) {
        const int n = (bkt << NPBS) + nl;
        if (n >= n_nodes) break;
        const int beg = ofs[nl];
        const int end = beg + hist[nl];

        float ax = 0.f, ay = 0.f;
        for (int i = beg; i < end; i += 8) {       // 8 row loads in flight
            unsigned vv[8]; bool val[8];
            #pragma unroll
            for (int j = 0; j < 8; ++j) {
                val[j] = (i + j) < end;
                int sid = srt[val[j] ? i + j : beg];   // uniform -> ds broadcast
                unsigned bo = ((unsigned)sid << 8) | lo4;
                vv[j] = *(const unsigned*)((const char*)hp + bo);
            }
            #pragma unroll
            for (int j = 0; j < 8; ++j) {
                if (val[j]) {
                    ax += __uint_as_float(vv[j] << 16);
                    ay += __uint_as_float(vv[j] & 0xffff0000u);
                }
            }
        }

        if (novf > 0) {                            // cold spill drain (never fires)
            int ne = min(novf, OVFCAP);
            for (int k = 0; k < ne; ++k) {
                if (ovf[1 + 2 * k] == n) {
                    int s = ovf[2 + 2 * k];
                    unsigned bo = ((unsigned)s << 8) | lo4;
                    unsigned u = *(const unsigned*)((const char*)hp + bo);
                    ax += __uint_as_float(u << 16);
                    ay += __uint_as_float(u & 0xffff0000u);
                }
            }
        }

        float rx = fmaxf(ax + bv.x, 0.f);
        float ry = fmaxf(ay + bv.y, 0.f);
        unsigned oo = ((unsigned)n << 9) | (lane << 3);
        *(float2*)((char*)out + oo) = make_float2(rx, ry);
    }
}

// ---------------------------------------------------------------------------
// Fallback tier (tiny ws or huge node ids): atomic scatter + fp32 GEMM.
// ---------------------------------------------------------------------------
__global__ void scatter_add_kernel(const float* __restrict__ h,
                                   const int* __restrict__ src,
                                   const int* __restrict__ dst,
                                   float* __restrict__ agg,
                                   long total) {
    long stride = (long)gridDim.x * blockDim.x;
    for (long i = (long)blockIdx.x * blockDim.x + threadIdx.x; i < total; i += stride) {
        int e    = (int)(i >> 5);
        int lane = (int)(i & 31);
        int s = src[e];
        int d = dst[e];
        float4 v = *(const float4*)(h + (long)s * F + (lane << 2));
        float* o = agg + (long)d * F + (lane << 2);
        unsafeAtomicAdd(o + 0, v.x);
        unsafeAtomicAdd(o + 1, v.y);
        unsafeAtomicAdd(o + 2, v.z);
        unsafeAtomicAdd(o + 3, v.w);
    }
}

__global__ __launch_bounds__(256) void gemm_bias_relu_inplace(
        float* __restrict__ out,
        const float* __restrict__ W,
        const float* __restrict__ bias,
        int n_rows) {
    __shared__ __align__(16) float a_t[KC][BR + 4];
    __shared__ __align__(16) float w_t[KC][F + 4];
    const int tid = threadIdx.x;
    const int tx = tid & 15;
    const int ty = tid >> 4;
    const int row0 = blockIdx.x * BR;
    float acc[4][8];
    #pragma unroll
    for (int i = 0; i < 4; ++i)
        #pragma unroll
        for (int j = 0; j < 8; ++j) acc[i][j] = 0.f;
    for (int kc = 0; kc < F; kc += KC) {
        #pragma unroll
        for (int p = 0; p < 2; ++p) {
            int q = tid + p * 256, r = q >> 3, kq = q & 7;
            int row = row0 + r;
            float4 v = make_float4(0.f, 0.f, 0.f, 0.f);
            if (row < n_rows) v = *(const float4*)(out + (long)row * F + kc + (kq << 2));
            a_t[kq * 4 + 0][r] = v.x; a_t[kq * 4 + 1][r] = v.y;
            a_t[kq * 4 + 2][r] = v.z; a_t[kq * 4 + 3][r] = v.w;
        }
        #pragma unroll
        for (int p = 0; p < 4; ++p) {
            int q = tid + p * 256, j = q >> 3, kq = q & 7;
            float4 v = *(const float4*)(W + (long)j * F + kc + (kq << 2));
            w_t[kq * 4 + 0][j] = v.x; w_t[kq * 4 + 1][j] = v.y;
            w_t[kq * 4 + 2][j] = v.z; w_t[kq * 4 + 3][j] = v.w;
        }
        __syncthreads();
        #pragma unroll
        for (int k = 0; k < KC; ++k) {
            float4 av = *(const float4*)&a_t[k][ty << 2];
            float4 w0 = *(const float4*)&w_t[k][tx << 2];
            float4 w1 = *(const float4*)&w_t[k][64 + (tx << 2)];
            float a4[4] = {av.x, av.y, av.z, av.w};
            float wv[8] = {w0.x, w0.y, w0.z, w0.w, w1.x, w1.y, w1.z, w1.w};
            #pragma unroll
            for (int i = 0; i < 4; ++i)
                #pragma unroll
                for (int j = 0; j < 8; ++j) acc[i][j] += a4[i] * wv[j];
        }
        __syncthreads();
    }
    float4 b0 = *(const float4*)(bias + (tx << 2));
    float4 b1 = *(const float4*)(bias + 64 + (tx << 2));
    #pragma unroll
    for (int i = 0; i < 4; ++i) {
        int row = row0 + (ty << 2) + i;
        if (row < n_rows) {
            float4 r0, r1;
            r0.x = fmaxf(acc[i][0] + b0.x, 0.f); r0.y = fmaxf(acc[i][1] + b0.y, 0.f);
            r0.z = fmaxf(acc[i][2] + b0.z, 0.f); r0.w = fmaxf(acc[i][3] + b0.w, 0.f);
            r1.x = fmaxf(acc[i][4] + b1.x, 0.f); r1.y = fmaxf(acc[i][5] + b1.y, 0.f);
            r1.z = fmaxf(acc[i][6] + b1.z, 0.f); r1.w = fmaxf(acc[i][7] + b1.w, 0.f);
            *(float4*)(out + (long)row * F + (tx << 2)) = r0;
            *(float4*)(out + (long)row * F + 64 + (tx << 2)) = r1;
        }
    }
}

extern "C" void kernel_launch(void* const* d_in, const int* in_sizes, int n_in,
                              void* d_out, int out_size, void* d_ws, size_t ws_size,
                              hipStream_t stream) {
    const float* h   = (const float*)d_in[0];
    const int*   src = (const int*)d_in[1];
    const int*   dst = (const int*)d_in[2];
    const float* W   = (const float*)d_in[3];
    const float* b   = (const float*)d_in[4];
    float* out = (float*)d_out;

    const int n_nodes = in_sizes[0] / F;
    const int n_edges = in_sizes[1];
    const int NB   = (n_nodes + NPB - 1) >> NPBS;
    const int NBLK = (n_edges + CHMAX - 1) / CHMAX;

    // ws layout: gcnt | ovf | cntmat | ebuf | hp (bf16 h@W^T) | Wb
    auto al16 = [](size_t x) { return (x + 15) & ~(size_t)15; };
    const size_t off_gcnt = 0;
    const size_t off_ovf  = al16((size_t)NB * 4);
    const size_t off_cmat = al16(off_ovf + 4 + (size_t)OVFCAP * 8);
    const size_t off_ebuf = al16(off_cmat + (size_t)NBLK * NB * 4);
    const size_t off_hp   = al16(off_ebuf + (size_t)NB * ECAP * 4);
    const size_t off_wb   = al16(off_hp + (size_t)n_nodes * F * 2);
    const size_t need     = off_wb + (size_t)F * F * 2;

    if (ws_size >= need && n_nodes > 0 && NB <= NBMAX) {
        int* gcnt = (int*)((char*)d_ws + off_gcnt);
        int* ovf  = (int*)((char*)d_ws + off_ovf);
        int* cmat = (int*)((char*)d_ws + off_cmat);
        int* ebuf = (int*)((char*)d_ws + off_ebuf);
        unsigned short* hp = (unsigned short*)((char*)d_ws + off_hp);
        unsigned short* Wb = (unsigned short*)((char*)d_ws + off_wb);

        hipMemsetAsync(ovf, 0, 4, stream);

        conv_w_kernel<<<(F * F / 4 + 255) / 256, 256, 0, stream>>>(W, Wb, F * F / 4);

        gemm_h_kernel<<<(n_nodes + 63) / 64, 256, 0, stream>>>(h, Wb, hp, n_nodes);

        if (NBLK > 0)
            count_kernel<<<NBLK, 1024, 0, stream>>>(dst, cmat, n_edges, NB);

        scan_kernel<<<NB, 256, 0, stream>>>(cmat, gcnt, NB, NBLK);

        if (NBLK > 0)
            scatter_kernel<<<NBLK, 1024, 0, stream>>>(src, dst, cmat, ebuf, ovf,
                                                      n_edges, NB);

        bucket_gather_kernel<<<NB, 1024, 0, stream>>>(hp, gcnt, ebuf, ovf, b,
                                                      out, n_nodes);
    } else {
        hipMemsetAsync(out, 0, (size_t)out_size * sizeof(float), stream);
        scatter_add_kernel<<<16384, 256, 0, stream>>>(
            h, src, dst, out, (long)n_edges * 32);
        const int gblocks = (n_nodes + BR - 1) / BR;
        gemm_bias_relu_inplace<<<gblocks, 256, 0, stream>>>(out, W, b, n_nodes);
    }
}